// Round 4
// baseline (289.825 us; speedup 1.0000x reference)
//
#include <hip/hip_runtime.h>
#include <hip/hip_bf16.h>
#include <stdint.h>

// Problem constants
#define NB   32
#define CIN  128
#define HIN  56
#define WIN  56
#define KOUT 256
#define HOUT 54
#define WOUT 54
#define PQ   (HOUT*WOUT)     // 2916
#define NPIX (NB*PQ)         // 93312
#define KK   (CIN*9)         // 1152
#define HW   (HIN*WIN)       // 3136
#define TWN_FACTOR 0.05f

typedef short bf16x8 __attribute__((ext_vector_type(8)));   // 8 bf16 = 4 VGPRs
typedef float f32x4  __attribute__((ext_vector_type(4)));

// ---- fused prep: blocks [0,288) absmax(|w|); blocks [288,1856) x NCHW->NHWC bf16 ----
__global__ void prep_k(const float* __restrict__ x, const float4* __restrict__ w4,
                       float* __restrict__ amax, __hip_bfloat16* __restrict__ xt) {
  __shared__ __hip_bfloat16 tl[64 * 130 + 32];   // stride 130 (odd dwords)
  __shared__ float sm[4];
  int bid = blockIdx.x;
  int t   = threadIdx.x;

  if (bid < 288) {                               // absmax part (w = 1.18 MB)
    float4 v = w4[bid * 256 + t];
    float m = fmaxf(fmaxf(fabsf(v.x), fabsf(v.y)), fmaxf(fabsf(v.z), fabsf(v.w)));
    #pragma unroll
    for (int off = 32; off > 0; off >>= 1)
      m = fmaxf(m, __shfl_down(m, off));
    int lane = t & 63, wv = t >> 6;
    if (lane == 0) sm[wv] = m;
    __syncthreads();
    if (t == 0)                                  // ws poison 0xAA.. is a tiny negative float
      atomicMax(amax, fmaxf(fmaxf(sm[0], sm[1]), fmaxf(sm[2], sm[3])));
    return;
  }

  int b2 = bid - 288;                            // 0..1567
  int n  = b2 / 49, pc = b2 - n * 49;            // image, 64-pixel chunk
  const float* xb = x + (size_t)n * CIN * HW + pc * 64;
  int f4 = t & 15, c0 = t >> 4;                  // phase 1: float4 along pixels
  #pragma unroll
  for (int rd = 0; rd < 8; ++rd) {
    int c = c0 + rd * 16;
    float4 v = *(const float4*)(xb + (size_t)c * HW + f4 * 4);  // 1KB/wave coalesced
    tl[(f4 * 4 + 0) * 130 + c] = __float2bfloat16(v.x);
    tl[(f4 * 4 + 1) * 130 + c] = __float2bfloat16(v.y);
    tl[(f4 * 4 + 2) * 130 + c] = __float2bfloat16(v.z);
    tl[(f4 * 4 + 3) * 130 + c] = __float2bfloat16(v.w);
  }
  __syncthreads();
  int cc = t & 15, p0 = t >> 4;                  // phase 2: b128 reads, 16B stores
  __hip_bfloat16* op = xt + ((size_t)n * HW + pc * 64) * CIN + cc * 8;
  #pragma unroll
  for (int p = p0; p < 64; p += 16)
    *(bf16x8*)(op + (size_t)p * CIN) = *(const bf16x8*)&tl[p * 130 + cc * 8];
}

// ---- quantize OIHW fp32 -> fragment-ordered qA[kc][256][8], kc = rs*16 + (c>>3) ----
__global__ void quant_k(const float* __restrict__ w, const float* __restrict__ amax,
                        __hip_bfloat16* __restrict__ qA) {
  float thr = TWN_FACTOR * (*amax);
  int t  = blockIdx.x * 256 + threadIdx.x;       // < 36864
  int kc = t >> 8, row = t & 255;
  int rs = kc >> 4, c0 = (kc & 15) << 3;
  bf16x8 q;
  #pragma unroll
  for (int j = 0; j < 8; ++j) {
    float v  = w[(size_t)(row * CIN + c0 + j) * 9 + rs];
    float qq = (v > thr) ? 1.f : ((v < -thr) ? -1.f : 0.f);
    q[j] = (short)__bfloat16_as_ushort(__float2bfloat16(qq));
  }
  *(bf16x8*)(qA + (size_t)t * 8) = q;            // 16B coalesced
}

// ---- implicit-GEMM conv: NO LDS, NO barriers. A and B both direct from L2. ----
// A: qA [144][256][8] fragment-ordered (quad-coalesced 256B).
// B: xt NHWC bf16 — one dwordx4/lane covers 16 fully-used 64B lines per instr.
__global__ __launch_bounds__(256) void conv_gemm(
    const __hip_bfloat16* __restrict__ xt,
    const __hip_bfloat16* __restrict__ qA,
    const float* __restrict__ bias,
    float* __restrict__ out) {
  const int tid  = threadIdx.x;
  const int wave = tid >> 6;
  const int lane = tid & 63;
  const int quad = lane >> 4;
  const int l16  = lane & 15;

  const int bid   = blockIdx.x;                  // 0..1457
  const int ktile = bid & 1;
  const int ptile = bid >> 1;
  const int k0    = ktile * 128;
  const int pbase = ptile * 128;

  const int wm = (wave >> 1) * 64;               // k_out sub-tile
  const int wn = (wave & 1) * 64;                // pixel sub-tile

  // B pixel base offsets (elements into xt), one per i-fragment; quad chunk added per h
  unsigned pb[4];
  #pragma unroll
  for (int i = 0; i < 4; ++i) {
    int pix = pbase + wn + i * 16 + l16;
    int n = pix / PQ; int rm = pix - n * PQ;
    int p = rm / WOUT; int q = rm - p * WOUT;
    pb[i] = (unsigned)(n * HW + p * WIN + q) * CIN + quad * 8;
  }

  // A fragment base offsets (elements into qA): (quad*256 + row)*8 + (rs*16+h*4)*2048
  unsigned aoff[4];
  #pragma unroll
  for (int i = 0; i < 4; ++i)
    aoff[i] = (unsigned)(quad * 256 + (k0 + wm + i * 16 + l16)) * 8;

  f32x4 acc[4][4];
  #pragma unroll
  for (int i = 0; i < 4; ++i)
    #pragma unroll
    for (int j = 0; j < 4; ++j)
      acc[i][j] = (f32x4){0.f, 0.f, 0.f, 0.f};

  #pragma unroll
  for (int rs = 0; rs < 9; ++rs) {
    const int r = rs / 3, s = rs - r * 3;
    const unsigned bstep = (unsigned)((r * WIN + s) * CIN);
    const unsigned astep = (unsigned)rs * 16 * 2048;

    #pragma unroll
    for (int h = 0; h < 4; ++h) {
      bf16x8 af[4], bfr[4];
      #pragma unroll
      for (int i = 0; i < 4; ++i)
        af[i] = *(const bf16x8*)(qA + aoff[i] + astep + (unsigned)h * 4 * 2048);
      #pragma unroll
      for (int i = 0; i < 4; ++i)
        bfr[i] = *(const bf16x8*)(xt + pb[i] + bstep + (unsigned)h * 32);
      #pragma unroll
      for (int i = 0; i < 4; ++i)
        #pragma unroll
        for (int j = 0; j < 4; ++j)
          acc[i][j] = __builtin_amdgcn_mfma_f32_16x16x32_bf16(af[i], bfr[j], acc[i][j], 0, 0, 0);
    }
  }

  // epilogue: D row=(quad*4+reg)=k_out_local, col=l16=pixel_local; + bias
  const float4* b4 = (const float4*)bias;
  #pragma unroll
  for (int j = 0; j < 4; ++j) {
    int pix  = pbase + wn + j * 16 + l16;
    int nimg = pix / PQ;
    int pq   = pix - nimg * PQ;
    size_t obase = (size_t)nimg * (KOUT * PQ) + pq;
    #pragma unroll
    for (int i = 0; i < 4; ++i) {
      int kb = k0 + wm + i * 16 + quad * 4;
      float4 bv = b4[kb >> 2];
      out[obase + (size_t)(kb + 0) * PQ] = acc[i][j][0] + bv.x;
      out[obase + (size_t)(kb + 1) * PQ] = acc[i][j][1] + bv.y;
      out[obase + (size_t)(kb + 2) * PQ] = acc[i][j][2] + bv.z;
      out[obase + (size_t)(kb + 3) * PQ] = acc[i][j][3] + bv.w;
    }
  }
}

extern "C" void kernel_launch(void* const* d_in, const int* in_sizes, int n_in,
                              void* d_out, int out_size, void* d_ws, size_t ws_size,
                              hipStream_t stream) {
  const float* x    = (const float*)d_in[0];
  const float* w    = (const float*)d_in[1];
  const float* bias = (const float*)d_in[2];
  float* out = (float*)d_out;

  // workspace: [0,4) amax float | [256,+25.7MB) xt bf16 | then qA bf16 (576KB)
  float* amax = (float*)d_ws;
  __hip_bfloat16* xt = (__hip_bfloat16*)((char*)d_ws + 256);
  __hip_bfloat16* qA = (__hip_bfloat16*)((char*)d_ws + 256 + (size_t)NB * HW * CIN * 2);

  prep_k  <<<dim3(1856), dim3(256), 0, stream>>>(x, (const float4*)w, amax, xt);
  quant_k <<<dim3(144),  dim3(256), 0, stream>>>(w, amax, qA);
  conv_gemm<<<dim3(1458), dim3(256), 0, stream>>>(xt, qA, bias, out);
}

// Round 5
// 218.640 us; speedup vs baseline: 1.3256x; 1.3256x over previous
//
#include <hip/hip_runtime.h>
#include <hip/hip_bf16.h>
#include <stdint.h>

// Problem constants
#define NB   32
#define CIN  128
#define HIN  56
#define WIN  56
#define KOUT 256
#define HOUT 54
#define WOUT 54
#define PQ   (HOUT*WOUT)     // 2916
#define NPIX (NB*PQ)         // 93312
#define KK   (CIN*9)         // 1152
#define HW   (HIN*WIN)       // 3136
#define TWN_FACTOR 0.05f

typedef short bf16x8 __attribute__((ext_vector_type(8)));   // 8 bf16 = 4 VGPRs
typedef float f32x4  __attribute__((ext_vector_type(4)));

// async global->LDS, 16B/lane; LDS dest = wave-uniform base + lane*16
__device__ __forceinline__ void glds16(const void* g, void* l) {
  __builtin_amdgcn_global_load_lds(
      (__attribute__((address_space(1))) void*)(g),
      (__attribute__((address_space(3))) void*)(l),
      16, 0, 0);
}

// ---- fused prep: blocks [0,288) absmax(|w|); blocks [288,1856) x NCHW->NHWC bf16 ----
__global__ void prep_k(const float* __restrict__ x, const float4* __restrict__ w4,
                       float* __restrict__ amax, __hip_bfloat16* __restrict__ xt) {
  __shared__ __hip_bfloat16 tl[64 * 130 + 32];   // stride 130 (odd dwords)
  __shared__ float sm[4];
  int bid = blockIdx.x;
  int t   = threadIdx.x;

  if (bid < 288) {                               // absmax part (w = 1.18 MB)
    float4 v = w4[bid * 256 + t];
    float m = fmaxf(fmaxf(fabsf(v.x), fabsf(v.y)), fmaxf(fabsf(v.z), fabsf(v.w)));
    #pragma unroll
    for (int off = 32; off > 0; off >>= 1)
      m = fmaxf(m, __shfl_down(m, off));
    int lane = t & 63, wv = t >> 6;
    if (lane == 0) sm[wv] = m;
    __syncthreads();
    if (t == 0)                                  // ws poison 0xAA.. is a tiny negative float
      atomicMax(amax, fmaxf(fmaxf(sm[0], sm[1]), fmaxf(sm[2], sm[3])));
    return;
  }

  int b2 = bid - 288;                            // 0..1567
  int n  = b2 / 49, pc = b2 - n * 49;            // image, 64-pixel chunk
  const float* xb = x + (size_t)n * CIN * HW + pc * 64;
  int f4 = t & 15, c0 = t >> 4;                  // phase 1: float4 along pixels
  #pragma unroll
  for (int rd = 0; rd < 8; ++rd) {
    int c = c0 + rd * 16;
    float4 v = *(const float4*)(xb + (size_t)c * HW + f4 * 4);  // 1KB/wave coalesced
    tl[(f4 * 4 + 0) * 130 + c] = __float2bfloat16(v.x);
    tl[(f4 * 4 + 1) * 130 + c] = __float2bfloat16(v.y);
    tl[(f4 * 4 + 2) * 130 + c] = __float2bfloat16(v.z);
    tl[(f4 * 4 + 3) * 130 + c] = __float2bfloat16(v.w);
  }
  __syncthreads();
  int cc = t & 15, p0 = t >> 4;                  // phase 2: b128 reads, 16B stores
  __hip_bfloat16* op = xt + ((size_t)n * HW + pc * 64) * CIN + cc * 8;
  #pragma unroll
  for (int p = p0; p < 64; p += 16)
    *(bf16x8*)(op + (size_t)p * CIN) = *(const bf16x8*)&tl[p * 130 + cc * 8];
}

// ---- quantize OIHW fp32 -> fragment-ordered qA[kc][256][8], kc = rs*16 + (c>>3) ----
__global__ void quant_k(const float* __restrict__ w, const float* __restrict__ amax,
                        __hip_bfloat16* __restrict__ qA) {
  float thr = TWN_FACTOR * (*amax);
  int t  = blockIdx.x * 256 + threadIdx.x;       // < 36864
  int kc = t >> 8, row = t & 255;
  int rs = kc >> 4, c0 = (kc & 15) << 3;
  bf16x8 q;
  #pragma unroll
  for (int j = 0; j < 8; ++j) {
    float v  = w[(size_t)(row * CIN + c0 + j) * 9 + rs];
    float qq = (v > thr) ? 1.f : ((v < -thr) ? -1.f : 0.f);
    q[j] = (short)__bfloat16_as_ushort(__float2bfloat16(qq));
  }
  *(bf16x8*)(qA + (size_t)t * 8) = q;            // 16B coalesced
}

// ---- implicit-GEMM conv: A direct-from-L2 fragments; B LDS double-buffered ----
// BK=64 per step, 18 steps, ONE barrier per step: glds(t+1) issued before
// compute(t), drained by the end-of-step barrier (overlapped with 32 MFMAs).
__global__ __launch_bounds__(256) void conv_gemm(
    const __hip_bfloat16* __restrict__ xt,
    const __hip_bfloat16* __restrict__ qA,       // [144][256][8] fragment-ordered
    const float* __restrict__ bias,
    float* __restrict__ out) {
  __shared__ __hip_bfloat16 Bs[2][128 * 64];     // 2 x 16 KB, XOR-swizzled 16B chunks

  const int tid  = threadIdx.x;
  const int wave = tid >> 6;
  const int lane = tid & 63;
  const int quad = lane >> 4;
  const int l16  = lane & 15;

  const int bid   = blockIdx.x;                  // 0..1457
  const int ktile = bid & 1;
  const int ptile = bid >> 1;
  const int k0    = ktile * 128;
  const int pbase = ptile * 128;

  const int wm = (wave >> 1) * 64;               // k_out sub-tile
  const int wn = (wave & 1) * 64;                // pixel sub-tile

  // B staging: 4 glds16/wave/step; each glds = 8 rows x 8 chunks (1 KB).
  // dest row = wave*32 + m*8 + (lane>>3); LDS pos (lane&7) holds global chunk pos^(row&7).
  const int r8 = lane >> 3;
  const int ch = lane & 7;
  unsigned boffm[4];
  #pragma unroll
  for (int m = 0; m < 4; ++m) {
    int row  = wave * 32 + m * 8 + r8;
    int prow = pbase + row;
    int n = prow / PQ; int rm = prow - n * PQ;
    int p = rm / WOUT; int q = rm - p * WOUT;
    boffm[m] = (unsigned)(n * HW + p * WIN + q) * CIN + ((ch ^ (row & 7)) << 3);
  }

  // A fragment base offsets (elements): quad*2048 + row*8
  unsigned aoff[4];
  #pragma unroll
  for (int i = 0; i < 4; ++i)
    aoff[i] = (unsigned)(quad * 256 + (k0 + wm + i * 16 + l16)) * 8;

  f32x4 acc[4][4];
  #pragma unroll
  for (int i = 0; i < 4; ++i)
    #pragma unroll
    for (int j = 0; j < 4; ++j)
      acc[i][j] = (f32x4){0.f, 0.f, 0.f, 0.f};

  // prologue: stage step 0 into buf 0
  {
    char* bdst = (char*)Bs[0] + wave * 4096;
    #pragma unroll
    for (int m = 0; m < 4; ++m)
      glds16(xt + boffm[m], bdst + m * 1024);    // step 0: (r,s)=(0,0), half 0
  }
  __syncthreads();

  #pragma unroll
  for (int t = 0; t < 18; ++t) {
    // prefetch step t+1 into the other buffer (drained by end-of-step barrier)
    if (t < 17) {
      const int tn  = t + 1;
      const int rsn = tn >> 1;
      const int rn  = rsn / 3, sn = rsn - rn * 3;
      const unsigned bst = (unsigned)((rn * WIN + sn) * CIN + (tn & 1) * 64);
      char* bdst = (char*)Bs[tn & 1] + wave * 4096;
      #pragma unroll
      for (int m = 0; m < 4; ++m)
        glds16(xt + boffm[m] + bst, bdst + m * 1024);
    }

    const char* bp = (const char*)Bs[t & 1];
    const unsigned astep = ((unsigned)(t >> 1) * 16 + (unsigned)(t & 1) * 8) * 2048;

    #pragma unroll
    for (int h = 0; h < 2; ++h) {
      bf16x8 af[4], bfr[4];
      #pragma unroll
      for (int i = 0; i < 4; ++i)                // A direct from L2, 256B/quad coalesced
        af[i] = *(const bf16x8*)(qA + aoff[i] + astep + (unsigned)h * 4 * 2048);
      #pragma unroll
      for (int i = 0; i < 4; ++i) {
        int row = wn + i * 16 + l16;
        bfr[i] = *(const bf16x8*)(bp + (row * 64 + (((h * 4 + quad) ^ (row & 7)) << 3)) * 2);
      }
      #pragma unroll
      for (int i = 0; i < 4; ++i)
        #pragma unroll
        for (int j = 0; j < 4; ++j)
          acc[i][j] = __builtin_amdgcn_mfma_f32_16x16x32_bf16(af[i], bfr[j], acc[i][j], 0, 0, 0);
    }
    __syncthreads();                             // drain prefetch; gate buffer reuse
  }

  // epilogue: D row=(quad*4+reg)=k_out_local, col=l16=pixel_local; + bias
  const float4* b4 = (const float4*)bias;
  #pragma unroll
  for (int j = 0; j < 4; ++j) {
    int pix  = pbase + wn + j * 16 + l16;
    int nimg = pix / PQ;
    int pq   = pix - nimg * PQ;
    size_t obase = (size_t)nimg * (KOUT * PQ) + pq;
    #pragma unroll
    for (int i = 0; i < 4; ++i) {
      int kb = k0 + wm + i * 16 + quad * 4;
      float4 bv = b4[kb >> 2];
      out[obase + (size_t)(kb + 0) * PQ] = acc[i][j][0] + bv.x;
      out[obase + (size_t)(kb + 1) * PQ] = acc[i][j][1] + bv.y;
      out[obase + (size_t)(kb + 2) * PQ] = acc[i][j][2] + bv.z;
      out[obase + (size_t)(kb + 3) * PQ] = acc[i][j][3] + bv.w;
    }
  }
}

extern "C" void kernel_launch(void* const* d_in, const int* in_sizes, int n_in,
                              void* d_out, int out_size, void* d_ws, size_t ws_size,
                              hipStream_t stream) {
  const float* x    = (const float*)d_in[0];
  const float* w    = (const float*)d_in[1];
  const float* bias = (const float*)d_in[2];
  float* out = (float*)d_out;

  // workspace: [0,4) amax float | [256,+25.7MB) xt bf16 | then qA bf16 (576KB)
  float* amax = (float*)d_ws;
  __hip_bfloat16* xt = (__hip_bfloat16*)((char*)d_ws + 256);
  __hip_bfloat16* qA = (__hip_bfloat16*)((char*)d_ws + 256 + (size_t)NB * HW * CIN * 2);

  prep_k  <<<dim3(1856), dim3(256), 0, stream>>>(x, (const float4*)w, amax, xt);
  quant_k <<<dim3(144),  dim3(256), 0, stream>>>(w, amax, qA);
  conv_gemm<<<dim3(1458), dim3(256), 0, stream>>>(xt, qA, bias, out);
}